// Round 7
// baseline (264.830 us; speedup 1.0000x reference)
//
#include <hip/hip_runtime.h>
#include <hip/hip_bf16.h>
#include <stdint.h>

#define G1CAST(p) ((const __attribute__((address_space(1))) void*)(p))
#define L3CAST(p) ((__attribute__((address_space(3))) void*)(p))

typedef short bf16x8 __attribute__((ext_vector_type(8)));
typedef float f32x16 __attribute__((ext_vector_type(16)));

// chunk swizzle for 128B rows (8x16B chunks): position = c ^ swz3(row)
__device__ __host__ __forceinline__ int swz3(int r) {
    return (r & 7) ^ (((r >> 3) & 1) << 2);
}

static __device__ __forceinline__ short f2bf(float f) {
    __hip_bfloat16 b = __float2bfloat16(f);
    return __builtin_bit_cast(short, b);
}

// ---------------------------------------------------------------------------
// Kernel 1: relayout+convert weights to bf16 (linear image).
// W_cat[n][gate][j][kk], kk in [0,1024): kk<512 -> W_ih[n][gate*512+j][kk]
//                                        kk>=512 -> W_hh[n][gate*512+j][kk-512]
// ---------------------------------------------------------------------------
__global__ __launch_bounds__(256) void wconv_kernel(const float* __restrict__ Wih,
                                                    const float* __restrict__ Whh,
                                                    short* __restrict__ Wcat) {
    const int tid = blockIdx.x * 256 + threadIdx.x;
    const int64_t e = (int64_t)tid * 8;
    const int kk = (int)(e & 1023);
    const int row = (int)(e >> 10);
    const int n = row / 1536;
    const int gr = row - n * 1536;
    const float* src = (kk < 512)
        ? Wih + ((int64_t)n * 786432 + (int64_t)gr * 512 + kk)
        : Whh + ((int64_t)n * 786432 + (int64_t)gr * 512 + (kk - 512));
    const float4 a = ((const float4*)src)[0];
    const float4 b = ((const float4*)src)[1];
    bf16x8 o;
    o[0] = f2bf(a.x); o[1] = f2bf(a.y); o[2] = f2bf(a.z); o[3] = f2bf(a.w);
    o[4] = f2bf(b.x); o[5] = f2bf(b.y); o[6] = f2bf(b.z); o[7] = f2bf(b.w);
    *(bf16x8*)(Wcat + e) = o;
}

// ---------------------------------------------------------------------------
// Kernel 1b: convert x,h -> bf16 pre-swizzled LDS images (256-row tiles).
// Tile t = (bt*8+nblk)*16+ks, 32 KB: [r 0..255][chunk c at pos c^swz3(r)][16B]
// ks<8 -> x k-slice ks, ks>=8 -> h k-slice ks-8 (64 cols each).
// ---------------------------------------------------------------------------
__global__ __launch_bounds__(256) void aconv_kernel(const float* __restrict__ x,
                                                    const float* __restrict__ h,
                                                    short* __restrict__ Aimg) {
    const int gid = blockIdx.x * 256 + threadIdx.x;   // 1,048,576 threads
    const int c4 = gid & 7;                           // 16B chunk in row
    const int r = (gid >> 3) & 255;                   // row in tile
    const int tile = gid >> 11;                       // 0..511
    const int ks = tile & 15;
    const int nblk = (tile >> 4) & 7;
    const int bt = tile >> 7;                         // 0..3
    const float* base = (ks < 8) ? x : h;
    const float* src = base + ((size_t)(bt * 256 + r) * 4096
                               + nblk * 512 + (ks & 7) * 64 + c4 * 8);
    const float4 a = ((const float4*)src)[0];
    const float4 b = ((const float4*)src)[1];
    bf16x8 o;
    o[0] = f2bf(a.x); o[1] = f2bf(a.y); o[2] = f2bf(a.z); o[3] = f2bf(a.w);
    o[4] = f2bf(b.x); o[5] = f2bf(b.y); o[6] = f2bf(b.z); o[7] = f2bf(b.w);
    *(bf16x8*)(Aimg + ((size_t)tile << 14) + r * 64 + (c4 ^ swz3(r)) * 8) = o;
}

// ---------------------------------------------------------------------------
// Kernel 2: fused block-diagonal GRU.
// BM=256 x BN=64, BK=64, 512 thr = 8 waves (4m x 2n), wave tile 64x32
// (m_rep=2, mfma_f32_32x32x16_bf16), acc = 128 regs.
// A dbuf (2x32K) + B ring-3 (3x24K) = 136 KB, 1 block/CU, grid 256.
// Counted vmcnt(3): B(i+1) never drained early; one barrier per K-step.
// Uniform 7 gld_lds per thread per step (4 A + 3 B).
// ---------------------------------------------------------------------------
__global__ __launch_bounds__(512, 2) void gru_kernel(
    const float* __restrict__ hst,
    const short* __restrict__ Wcat, const short* __restrict__ Aimg,
    const float* __restrict__ b_ih, const float* __restrict__ b_hh,
    float* __restrict__ out)
{
    __shared__ short ldsA[2][256 * 64];       // 2 x 32 KB  [r][128B swz row]
    __shared__ short ldsB[3][3 * 64 * 64];    // 3 x 24 KB  [g][j][128B swz row]

    const int tid = threadIdx.x;
    const int nblk = blockIdx.x & 7;          // XCD-local weight slice
    const int rr_ = blockIdx.x >> 3;          // 0..31
    const int jt = rr_ & 7;                   // j tile (fast -> A L2 reuse)
    const int bt = rr_ >> 3;                  // 0..3 batch tile (slow)
    const int j0b = jt * 64;
    const int brow0 = bt * 256;

    const int lane = tid & 63;
    const int wave = tid >> 6;                // 0..7
    const int wm = wave >> 1;                 // 0..3 (64-row slice)
    const int wn = wave & 1;                  // 0..1 (32-col slice)
    const int l31 = lane & 31;
    const int k8 = lane >> 5;

    // B staging: 3 chunks/thread; dest chunk q=tid+512u -> gate u, j=tid>>3,
    // c=tid&7; source chunk pre-swizzled so LDS stays linear.
    uint32_t bsrc[3];
    {
        const int j = tid >> 3;
        const int c = tid & 7;
        #pragma unroll
        for (int u = 0; u < 3; ++u)
            bsrc[u] = (uint32_t)(((nblk * 1536 + u * 512 + j0b + j) * 1024
                                  + (c ^ swz3(j)) * 8) * 2);   // bytes
    }
    const size_t a_tile0 = ((size_t)(bt * 8 + nblk)) << 19;    // 16 tiles x 32KB

    f32x16 acc_r[2] = {};
    f32x16 acc_z[2] = {};
    f32x16 acc_nx[2] = {};
    f32x16 acc_nh[2] = {};

    auto stageA = [&](int buf, int ks) {
        const char* as = (const char*)Aimg + a_tile0 + ((size_t)ks << 15) + (size_t)tid * 16;
        char* ad = (char*)&ldsA[buf][0] + tid * 16;
        #pragma unroll
        for (int u = 0; u < 4; ++u)
            __builtin_amdgcn_global_load_lds(G1CAST(as + u * 8192), L3CAST(ad + u * 8192), 16, 0, 0);
    };
    auto stageB = [&](int slot, int ks) {
        const char* wsb = (const char*)Wcat + (size_t)ks * 128;   // k offset, bytes
        char* bd = (char*)&ldsB[slot][0] + tid * 16;
        #pragma unroll
        for (int u = 0; u < 3; ++u)
            __builtin_amdgcn_global_load_lds(G1CAST(wsb + bsrc[u]), L3CAST(bd + u * 8192), 16, 0, 0);
    };

    // per-thread read offsets
    const int arow0 = wm * 64 + l31;
    const int arow1 = arow0 + 32;
    const int jrow = wn * 32 + l31;
    const int swA0 = swz3(arow0), swA1 = swz3(arow1), swB = swz3(jrow);
    const int abase0 = arow0 * 128, abase1 = arow1 * 128;
    const int bbase = jrow * 128;

    auto computeStep = [&](const short* Ab_s, const short* Bb_s, f32x16 (&accN)[2]) {
        const char* Ab = (const char*)Ab_s;
        const char* Bb = (const char*)Bb_s;
        #pragma unroll
        for (int ksub = 0; ksub < 4; ++ksub) {
            const int ch = ksub * 2 + k8;
            bf16x8 af0 = *(const bf16x8*)(Ab + abase0 + ((ch ^ swA0) << 4));
            bf16x8 af1 = *(const bf16x8*)(Ab + abase1 + ((ch ^ swA1) << 4));
            bf16x8 b0 = *(const bf16x8*)(Bb + 0 * 8192 + bbase + ((ch ^ swB) << 4));
            bf16x8 b1 = *(const bf16x8*)(Bb + 1 * 8192 + bbase + ((ch ^ swB) << 4));
            bf16x8 b2 = *(const bf16x8*)(Bb + 2 * 8192 + bbase + ((ch ^ swB) << 4));
            __builtin_amdgcn_s_setprio(1);
            acc_r[0] = __builtin_amdgcn_mfma_f32_32x32x16_bf16(af0, b0, acc_r[0], 0, 0, 0);
            acc_r[1] = __builtin_amdgcn_mfma_f32_32x32x16_bf16(af1, b0, acc_r[1], 0, 0, 0);
            acc_z[0] = __builtin_amdgcn_mfma_f32_32x32x16_bf16(af0, b1, acc_z[0], 0, 0, 0);
            acc_z[1] = __builtin_amdgcn_mfma_f32_32x32x16_bf16(af1, b1, acc_z[1], 0, 0, 0);
            accN[0]  = __builtin_amdgcn_mfma_f32_32x32x16_bf16(af0, b2, accN[0], 0, 0, 0);
            accN[1]  = __builtin_amdgcn_mfma_f32_32x32x16_bf16(af1, b2, accN[1], 0, 0, 0);
            __builtin_amdgcn_s_setprio(0);
        }
    };

    // prologue: A(0) + B(0), B(1) in flight
    stageA(0, 0); stageB(0, 0); stageB(1, 1);

    // steady state: wait A(i),B(i) landed (leave B(i+1) flying), barrier,
    // issue A(i+1) + B(i+2), compute(i).
    #pragma unroll 1
    for (int i = 0; i < 14; ++i) {
        asm volatile("s_waitcnt vmcnt(3)" ::: "memory");
        __builtin_amdgcn_sched_barrier(0);
        __builtin_amdgcn_s_barrier();
        __builtin_amdgcn_sched_barrier(0);
        stageA((i + 1) & 1, i + 1);
        stageB((i + 2) % 3, i + 2);
        if (i < 8) computeStep(ldsA[i & 1], ldsB[i % 3], acc_nx);
        else       computeStep(ldsA[i & 1], ldsB[i % 3], acc_nh);
    }
    // i = 14: no B(16); issue A(15) only
    asm volatile("s_waitcnt vmcnt(3)" ::: "memory");
    __builtin_amdgcn_sched_barrier(0);
    __builtin_amdgcn_s_barrier();
    __builtin_amdgcn_sched_barrier(0);
    stageA(1, 15);
    computeStep(ldsA[0], ldsB[2], acc_nh);
    // i = 15: full drain
    asm volatile("s_waitcnt vmcnt(0)" ::: "memory");
    __builtin_amdgcn_sched_barrier(0);
    __builtin_amdgcn_s_barrier();
    __builtin_amdgcn_sched_barrier(0);
    computeStep(ldsA[1], ldsB[0], acc_nh);

    // ---- epilogue: gates + output (wave owns 64x32 tile) ----
    const int jb = j0b + wn * 32 + l31;       // [0,512)
    const int bb = nblk * 1536 + jb;
    const float br = b_ih[bb] + b_hh[bb];
    const float bz = b_ih[bb + 512] + b_hh[bb + 512];
    const float bnx = b_ih[bb + 1024];
    const float bnh = b_hh[bb + 1024];
    const int gcol = nblk * 512 + jb;
    #pragma unroll
    for (int m = 0; m < 2; ++m) {
        #pragma unroll
        for (int rr = 0; rr < 16; ++rr) {
            const int rowl = (rr & 3) + 8 * (rr >> 2) + 4 * k8;
            const int row = brow0 + wm * 64 + m * 32 + rowl;
            const size_t idx = (size_t)row * 4096 + gcol;
            const float sr = acc_r[m][rr] + br;
            const float sz = acc_z[m][rr] + bz;
            const float rg = 1.f / (1.f + __expf(-sr));
            const float zg = 1.f / (1.f + __expf(-sz));
            const float tin = (acc_nx[m][rr] + bnx) + rg * (acc_nh[m][rr] + bnh);
            const float e2 = __expf(-2.f * tin);
            const float ng = 2.f / (1.f + e2) - 1.f;
            const float hv = hst[idx];
            out[idx] = ng + zg * (hv - ng);
        }
    }
}

extern "C" void kernel_launch(void* const* d_in, const int* in_sizes, int n_in,
                              void* d_out, int out_size, void* d_ws, size_t ws_size,
                              hipStream_t stream) {
    (void)in_sizes; (void)n_in; (void)out_size; (void)ws_size;
    const float* x    = (const float*)d_in[0];
    const float* h    = (const float*)d_in[1];
    const float* W_ih = (const float*)d_in[2];
    const float* W_hh = (const float*)d_in[3];
    const float* b_ih = (const float*)d_in[4];
    const float* b_hh = (const float*)d_in[5];
    short* Wcat = (short*)d_ws;                              // 24 MB
    short* Aimg = (short*)d_ws + (size_t)12 * 1024 * 1024;   // 16 MB

    wconv_kernel<<<6144, 256, 0, stream>>>(W_ih, W_hh, Wcat);
    aconv_kernel<<<4096, 256, 0, stream>>>(x, h, Aimg);
    gru_kernel<<<256, 512, 0, stream>>>(h, Wcat, Aimg, b_ih, b_hh, (float*)d_out);
}

// Round 8
// 111.724 us; speedup vs baseline: 2.3704x; 2.3704x over previous
//
#include <hip/hip_runtime.h>
#include <hip/hip_bf16.h>
#include <stdint.h>

typedef short bf16x8 __attribute__((ext_vector_type(8)));
typedef float f32x16 __attribute__((ext_vector_type(16)));

static __device__ __forceinline__ short f2bf(float f) {
    __hip_bfloat16 b = __float2bfloat16(f);
    return __builtin_bit_cast(short, b);
}

// ---------------------------------------------------------------------------
// Kernel 1: weights -> bf16 in exact MFMA-fragment order.
// Slot index (one 16B slot per thread):
//   gid = ((((nblk*16 + jt*2 + wn)*3 + g)*16 + ks)*4 + ksub)*64 + lane
// Fragment semantics (mfma_f32_32x32x16_bf16 B operand):
//   j  = jt*64 + wn*32 + (lane&31)
//   kk = ks*64 + ksub*16 + (lane>>5)*8 + t,  t = 0..7
//   kk < 512 -> W_ih[nblk][g*512+j][kk], else W_hh[nblk][g*512+j][kk-512]
// ---------------------------------------------------------------------------
__global__ __launch_bounds__(256) void wconv_kernel(const float* __restrict__ Wih,
                                                    const float* __restrict__ Whh,
                                                    short* __restrict__ Wfrag) {
    const int gid = blockIdx.x * 256 + threadIdx.x;   // 1,572,864 threads
    const int lane = gid & 63;
    const int ksub = (gid >> 6) & 3;
    const int ks   = (gid >> 8) & 15;
    int s = gid >> 12;                                // 0..383
    const int g = s % 3; s /= 3;                      // 0..127
    const int wn = s & 1;
    const int jt = (s >> 1) & 7;
    const int nblk = s >> 4;
    const int j = jt * 64 + wn * 32 + (lane & 31);
    const int kk = ks * 64 + ksub * 16 + (lane >> 5) * 8;
    const float* src = (kk < 512)
        ? Wih + ((int64_t)nblk * 786432 + (int64_t)(g * 512 + j) * 512 + kk)
        : Whh + ((int64_t)nblk * 786432 + (int64_t)(g * 512 + j) * 512 + (kk - 512));
    const float4 a = ((const float4*)src)[0];
    const float4 b = ((const float4*)src)[1];
    bf16x8 o;
    o[0] = f2bf(a.x); o[1] = f2bf(a.y); o[2] = f2bf(a.z); o[3] = f2bf(a.w);
    o[4] = f2bf(b.x); o[5] = f2bf(b.y); o[6] = f2bf(b.z); o[7] = f2bf(b.w);
    *(bf16x8*)(Wfrag + (size_t)gid * 8) = o;
}

// ---------------------------------------------------------------------------
// Kernel 2: fused block-diagonal GRU — LDS-FREE.
// BM=128 x BN=64(x3 gates), 256 thr = 4 waves (2m x 2n), wave tile 64x32,
// m_rep=2, mfma_f32_32x32x16_bf16, acc = 8 x f32x16 = 128 AGPRs.
// B-fragments: coalesced b128 loads from fragment-ordered Wfrag (L2-resident,
// XCD-pinned). A-fragments: 8 consecutive fp32 per lane from x/h + inline
// f2bf. No LDS, no barriers; latency hidden by compiler pipelining + TLP.
// ---------------------------------------------------------------------------
__global__ __launch_bounds__(256, 2) void gru_kernel(
    const float* __restrict__ x, const float* __restrict__ hst,
    const short* __restrict__ Wfrag,
    const float* __restrict__ b_ih, const float* __restrict__ b_hh,
    float* __restrict__ out)
{
    const int tid = threadIdx.x;
    const int nblk = blockIdx.x & 7;          // XCD-local weight slice
    const int rr_ = blockIdx.x >> 3;          // 0..63
    const int bt = rr_ >> 3;                  // batch tile (slow)
    const int jt = rr_ & 7;                   // j tile (fast -> A L2 reuse)
    const int brow0 = bt * 128;

    const int lane = tid & 63;
    const int wave = tid >> 6;                // 0..3
    const int wm = wave >> 1;                 // 0..1 (64-row slice)
    const int wn = wave & 1;                  // 0..1 (32-col slice)
    const int l31 = lane & 31;
    const int k8 = lane >> 5;

    const int arow0 = brow0 + wm * 64 + l31;
    const int arow1 = arow0 + 32;
    const float* xr0 = x + (size_t)arow0 * 4096 + nblk * 512;
    const float* xr1 = x + (size_t)arow1 * 4096 + nblk * 512;
    const float* hr0 = hst + (size_t)arow0 * 4096 + nblk * 512;
    const float* hr1 = hst + (size_t)arow1 * 4096 + nblk * 512;

    // fragment base for this (nblk, jt, wn): per-gate stride 64 KB
    const char* wbase = (const char*)Wfrag
        + ((size_t)(nblk * 16 + jt * 2 + wn) * 3 << 16) + (size_t)lane * 16;

    f32x16 acc_r[2] = {};
    f32x16 acc_z[2] = {};
    f32x16 acc_nx[2] = {};
    f32x16 acc_nh[2] = {};

    auto phase = [&](const float* r0, const float* r1, int ksbase, f32x16 (&accN)[2]) {
        #pragma unroll 2
        for (int ks = 0; ks < 8; ++ks) {
            const float* p0 = r0 + ks * 64;
            const float* p1 = r1 + ks * 64;
            const char* wk = wbase + (size_t)(ksbase + ks) * 4096;
            #pragma unroll
            for (int ksub = 0; ksub < 4; ++ksub) {
                const int co = (ksub * 2 + k8) * 8;
                const float4 a00 = *(const float4*)(p0 + co);
                const float4 a01 = *(const float4*)(p0 + co + 4);
                const float4 a10 = *(const float4*)(p1 + co);
                const float4 a11 = *(const float4*)(p1 + co + 4);
                bf16x8 af0, af1;
                af0[0] = f2bf(a00.x); af0[1] = f2bf(a00.y); af0[2] = f2bf(a00.z); af0[3] = f2bf(a00.w);
                af0[4] = f2bf(a01.x); af0[5] = f2bf(a01.y); af0[6] = f2bf(a01.z); af0[7] = f2bf(a01.w);
                af1[0] = f2bf(a10.x); af1[1] = f2bf(a10.y); af1[2] = f2bf(a10.z); af1[3] = f2bf(a10.w);
                af1[4] = f2bf(a11.x); af1[5] = f2bf(a11.y); af1[6] = f2bf(a11.z); af1[7] = f2bf(a11.w);
                const bf16x8 b0 = *(const bf16x8*)(wk + ksub * 1024 + 0 * 65536);
                const bf16x8 b1 = *(const bf16x8*)(wk + ksub * 1024 + 1 * 65536);
                const bf16x8 b2 = *(const bf16x8*)(wk + ksub * 1024 + 2 * 65536);
                acc_r[0] = __builtin_amdgcn_mfma_f32_32x32x16_bf16(af0, b0, acc_r[0], 0, 0, 0);
                acc_r[1] = __builtin_amdgcn_mfma_f32_32x32x16_bf16(af1, b0, acc_r[1], 0, 0, 0);
                acc_z[0] = __builtin_amdgcn_mfma_f32_32x32x16_bf16(af0, b1, acc_z[0], 0, 0, 0);
                acc_z[1] = __builtin_amdgcn_mfma_f32_32x32x16_bf16(af1, b1, acc_z[1], 0, 0, 0);
                accN[0]  = __builtin_amdgcn_mfma_f32_32x32x16_bf16(af0, b2, accN[0], 0, 0, 0);
                accN[1]  = __builtin_amdgcn_mfma_f32_32x32x16_bf16(af1, b2, accN[1], 0, 0, 0);
            }
        }
    };

    phase(xr0, xr1, 0, acc_nx);   // k 0..511   (W_ih half)
    phase(hr0, hr1, 8, acc_nh);   // k 512..1023 (W_hh half)

    // ---- epilogue: gates + output (wave owns 64x32 tile) ----
    const int jb = jt * 64 + wn * 32 + l31;   // [0,512)
    const int bb = nblk * 1536 + jb;
    const float br = b_ih[bb] + b_hh[bb];
    const float bz = b_ih[bb + 512] + b_hh[bb + 512];
    const float bnx = b_ih[bb + 1024];
    const float bnh = b_hh[bb + 1024];
    const int gcol = nblk * 512 + jb;
    #pragma unroll
    for (int m = 0; m < 2; ++m) {
        #pragma unroll
        for (int rr = 0; rr < 16; ++rr) {
            const int rowl = (rr & 3) + 8 * (rr >> 2) + 4 * k8;
            const int row = brow0 + wm * 64 + m * 32 + rowl;
            const size_t idx = (size_t)row * 4096 + gcol;
            const float sr = acc_r[m][rr] + br;
            const float sz = acc_z[m][rr] + bz;
            const float rg = 1.f / (1.f + __expf(-sr));
            const float zg = 1.f / (1.f + __expf(-sz));
            const float tin = (acc_nx[m][rr] + bnx) + rg * (acc_nh[m][rr] + bnh);
            const float e2 = __expf(-2.f * tin);
            const float ng = 2.f / (1.f + e2) - 1.f;
            const float hv = hst[idx];
            out[idx] = ng + zg * (hv - ng);
        }
    }
}

extern "C" void kernel_launch(void* const* d_in, const int* in_sizes, int n_in,
                              void* d_out, int out_size, void* d_ws, size_t ws_size,
                              hipStream_t stream) {
    (void)in_sizes; (void)n_in; (void)out_size; (void)ws_size;
    const float* x    = (const float*)d_in[0];
    const float* h    = (const float*)d_in[1];
    const float* W_ih = (const float*)d_in[2];
    const float* W_hh = (const float*)d_in[3];
    const float* b_ih = (const float*)d_in[4];
    const float* b_hh = (const float*)d_in[5];
    short* Wfrag = (short*)d_ws;              // 24 MB, fragment-ordered bf16

    wconv_kernel<<<6144, 256, 0, stream>>>(W_ih, W_hh, Wfrag);
    gru_kernel<<<512, 256, 0, stream>>>(x, h, Wfrag, b_ih, b_hh, (float*)d_out);
}